// Round 15
// baseline (59.817 us; speedup 1.0000x reference)
//
#include <hip/hip_runtime.h>

#define Cc 8
#define Hh 128
#define Ww 128
#define Nn 64
#define Bb 8
#define Dd 169            // (C+2)*C + C + C*C + C + C + 1
#define HW (Hh * Ww)
#define NP 4              // n-pairs per block
#define NPG 8             // n-pair groups per batch (32/NP)
#define PXS 512           // pixels per stripe (block)
#define NSTRIPE (HW / PXS)          // 32
#define NBLK (Bb * NPG * NSTRIPE)   // 2048 blocks
#define FRAGW 16                    // u32 per lane per n-pair in frag table
#define FRAG_U32 (256 * 64 * FRAGW) // 256 n-pairs total
#define SLOTS (NPG * NSTRIPE)       // 256 reduction slots per batch

#define INV128 (1.0f / 128.0f)

typedef __fp16 f16x2 __attribute__((ext_vector_type(2)));
typedef _Float16 h8 __attribute__((ext_vector_type(8)));
typedef float f32x4 __attribute__((ext_vector_type(4)));

static __device__ __forceinline__ uint32_t pku(float a, float b) {
    f16x2 t = __builtin_amdgcn_cvt_pkrtz(a, b);
    uint32_t u; __builtin_memcpy(&u, &t, 4); return u;
}
static __device__ __forceinline__ h8 u4h8(uint32_t a, uint32_t b, uint32_t c, uint32_t d) {
    uint32_t u[4] = {a, b, c, d}; h8 r; __builtin_memcpy(&r, u, 16); return r;
}

// ---- kernel A: per-lane MFMA fragments per n-pair (layout validated r14) ----
// Slots/lane: [0..3]=A1, [4..5]=A2, [6..9]=w3slice f32, [10..13]=C2(b2) f32,
//             [14]=b3 f32, [15]=m^2 of lane's n (ALL lanes — r15: dice de-dup)
__global__ void pack_frags(const float* __restrict__ conv_weight,
                           const float* __restrict__ mask,
                           const int*   __restrict__ ind,
                           uint32_t*    __restrict__ frag) {
    const int npair = blockIdx.x;            // 0..255
    const int b     = npair >> 5;
    const int bn0   = b * Nn + 2 * (npair & 31);
    const int l  = threadIdx.x;              // 0..63
    const int g  = l >> 4, r = l & 15, rr = r & 7;
    const int bnr = bn0 + (r >> 3);          // row-owner n
    const int bng = bn0 + (g >> 1);          // D-row-group owner n
    const float* base = conv_weight + (size_t)b * Dd * HW;
    const float* srcR = base + ind[bnr];
    const float* srcG = base + ind[bng];

    float a1[8];
    #pragma unroll
    for (int e = 0; e < 8; ++e) {
        const int k = 8 * g + e;
        float v = 0.f;
        if (k < 8)       v = srcR[(size_t)(rr * 10 + k) * HW];
        else if (k == 8) v = srcR[(size_t)(rr * 10 + 8) * HW];
        else if (k == 9) v = srcR[(size_t)(rr * 10 + 9) * HW];
        else if (k == 10) {
            const float w8 = srcR[(size_t)(rr * 10 + 8) * HW];
            const float w9 = srcR[(size_t)(rr * 10 + 9) * HW];
            const float b1 = srcR[(size_t)(80 + rr) * HW];
            const int   ib = ind[bnr];
            v = b1 - w8 * ((float)(ib & 127) * INV128)
                   - w9 * ((float)(ib >> 7) * INV128);
        }
        a1[e] = v;
    }
    float a2[4];
    #pragma unroll
    for (int e = 0; e < 4; ++e) {
        const int k2 = 4 * g + e;
        float v = 0.f;
        if (r < 8)  { if (k2 < 8)  v = srcR[(size_t)(88 + rr * 8 + k2) * HW]; }
        else        { if (k2 >= 8) v = srcR[(size_t)(88 + rr * 8 + (k2 - 8)) * HW]; }
        a2[e] = v;
    }
    float w3v[4], c2v[4];
    #pragma unroll
    for (int j = 0; j < 4; ++j) {
        const int c = (4 * g + j) & 7;
        w3v[j] = srcG[(size_t)(160 + c) * HW];
        c2v[j] = srcG[(size_t)(152 + c) * HW];
    }
    const float b3 = srcG[(size_t)168 * HW];
    const float mm = mask[bng];
    const float fl = mm * mm;                // un-gated: every lane owns one dice elem

    uint32_t* dst = frag + ((size_t)npair * 64 + l) * FRAGW;
    dst[0] = pku(a1[0], a1[1]); dst[1] = pku(a1[2], a1[3]);
    dst[2] = pku(a1[4], a1[5]); dst[3] = pku(a1[6], a1[7]);
    dst[4] = pku(a2[0], a2[1]); dst[5] = pku(a2[2], a2[3]);
    float* df = (float*)dst;
    df[6] = w3v[0]; df[7] = w3v[1]; df[8] = w3v[2]; df[9] = w3v[3];
    df[10] = c2v[0]; df[11] = c2v[1]; df[12] = c2v[2]; df[13] = c2v[3];
    df[14] = b3; df[15] = fl;
}

// ---- kernel B: MFMA main, paired-unit dice de-dup, hoisted pointers ----
__global__ __launch_bounds__(256)
void seg_dice_main(const float* __restrict__ seg_feat,
                   const float* __restrict__ target,
                   const uint32_t* __restrict__ frag,
                   float* __restrict__ red_base) {
    const int bid    = blockIdx.x;
    const int b      = bid & 7;
    const int rest   = bid >> 3;           // 0..255
    const int npg    = rest & 7;
    const int stripe = rest >> 3;          // 0..31
    const int p0     = stripe * PXS;
    const int tid  = threadIdx.x;
    const int wave = tid >> 6;
    const int l    = tid & 63;
    const int g    = l >> 4, col = l & 15;

    __shared__ uint4 lds4[PXS];            // pixel-major seg tile: 8 f16/px

    const float* seg_b = seg_feat + (size_t)b * Cc * HW;
    #pragma unroll
    for (int q = 0; q < 2; ++q) {
        const int px = q * 256 + tid;
        float v[8];
        #pragma unroll
        for (int c = 0; c < 8; ++c) v[c] = seg_b[(size_t)c * HW + p0 + px];
        lds4[px] = uint4{pku(v[0], v[1]), pku(v[2], v[3]),
                         pku(v[4], v[5]), pku(v[6], v[7])};
    }

    // per-lane fragments for NP n-pairs
    const int npair0 = b * 32 + npg * NP;
    uint32_t A1u[NP][4], A2u[NP][2];
    float w3v[NP][4], c2v[NP][4], b3v[NP], flv[NP];
    #pragma unroll
    for (int j = 0; j < NP; ++j) {
        const uint4* fp = (const uint4*)(frag + ((size_t)(npair0 + j) * 64 + l) * FRAGW);
        const uint4 q0 = fp[0], q1 = fp[1], q2 = fp[2], q3 = fp[3];
        A1u[j][0] = q0.x; A1u[j][1] = q0.y; A1u[j][2] = q0.z; A1u[j][3] = q0.w;
        A2u[j][0] = q1.x; A2u[j][1] = q1.y;
        w3v[j][0] = __uint_as_float(q1.z); w3v[j][1] = __uint_as_float(q1.w);
        w3v[j][2] = __uint_as_float(q2.x); w3v[j][3] = __uint_as_float(q2.y);
        c2v[j][0] = __uint_as_float(q2.z); c2v[j][1] = __uint_as_float(q2.w);
        c2v[j][2] = __uint_as_float(q3.x); c2v[j][3] = __uint_as_float(q3.y);
        b3v[j] = __uint_as_float(q3.z);
        flv[j] = __uint_as_float(q3.w);
    }

    // hoisted per-lane dice ownership: slot s covers units {2s, 2s+1};
    // lane owns (jj = 2s + (g&1), n = l>>5, col)
    const int par = g & 1;
    float flS[2], b3S[2];
    const float* ptrS[2];
    #pragma unroll
    for (int s = 0; s < 2; ++s) {
        const int jj = 2 * s + par;
        flS[s] = par ? flv[2 * s + 1] : flv[2 * s];
        b3S[s] = par ? b3v[2 * s + 1] : b3v[2 * s];
        const int bnS = b * Nn + 2 * (npg * NP + jj) + (l >> 5);
        ptrS[s] = target + (size_t)bnS * HW + p0 + col;
    }
    __syncthreads();

    const f32x4 ZF = {0.f, 0.f, 0.f, 0.f};
    float inter = 0.f, ps = 0.f, ts = 0.f;

    #pragma unroll 1
    for (int tt = wave; tt < PXS / 16; tt += 4) {
        const int pxt = tt * 16;
        const int pxg = p0 + pxt + col;

        const uint4 d = lds4[pxt + col];
        const uint32_t xv = pku((float)(pxg & 127) * INV128,
                                (float)(pxg >> 7) * INV128);
        const uint32_t ov = pku(1.f, 0.f);
        const uint32_t e0 = (g == 0) ? d.x : ((g == 1) ? xv : 0u);
        const uint32_t e1 = (g == 0) ? d.y : ((g == 1) ? ov : 0u);
        const uint32_t e2 = (g == 0) ? d.z : 0u;
        const uint32_t e3 = (g == 0) ? d.w : 0u;
        const h8 B1 = u4h8(e0, e1, e2, e3);

        #pragma unroll
        for (int s = 0; s < 2; ++s) {
            const int jA = 2 * s, jB = 2 * s + 1;
            const h8 A1a = u4h8(A1u[jA][0], A1u[jA][1], A1u[jA][2], A1u[jA][3]);
            const h8 A1b = u4h8(A1u[jB][0], A1u[jB][1], A1u[jB][2], A1u[jB][3]);
            f32x4 h1a = __builtin_amdgcn_mfma_f32_16x16x32_f16(A1a, B1, ZF, 0, 0, 0);
            f32x4 h1b = __builtin_amdgcn_mfma_f32_16x16x32_f16(A1b, B1, ZF, 0, 0, 0);
            #pragma unroll
            for (int e = 0; e < 4; ++e) {
                h1a[e] = fmaxf(h1a[e], 0.f);
                h1b[e] = fmaxf(h1b[e], 0.f);
            }
            const h8 B2a = u4h8(pku(h1a[0], h1a[1]), pku(h1a[2], h1a[3]), 0u, 0u);
            const h8 B2b = u4h8(pku(h1b[0], h1b[1]), pku(h1b[2], h1b[3]), 0u, 0u);
            const h8 A2a = u4h8(A2u[jA][0], A2u[jA][1], 0u, 0u);
            const h8 A2b = u4h8(A2u[jB][0], A2u[jB][1], 0u, 0u);
            f32x4 c2a; c2a[0] = c2v[jA][0]; c2a[1] = c2v[jA][1];
                       c2a[2] = c2v[jA][2]; c2a[3] = c2v[jA][3];
            f32x4 c2b; c2b[0] = c2v[jB][0]; c2b[1] = c2v[jB][1];
                       c2b[2] = c2v[jB][2]; c2b[3] = c2v[jB][3];
            f32x4 h2a = __builtin_amdgcn_mfma_f32_16x16x32_f16(A2a, B2a, c2a, 0, 0, 0);
            f32x4 h2b = __builtin_amdgcn_mfma_f32_16x16x32_f16(A2b, B2b, c2b, 0, 0, 0);

            float zpa = fmaxf(h2a[0], 0.f) * w3v[jA][0];
            zpa = fmaf(fmaxf(h2a[1], 0.f), w3v[jA][1], zpa);
            zpa = fmaf(fmaxf(h2a[2], 0.f), w3v[jA][2], zpa);
            zpa = fmaf(fmaxf(h2a[3], 0.f), w3v[jA][3], zpa);
            float zpb = fmaxf(h2b[0], 0.f) * w3v[jB][0];
            zpb = fmaf(fmaxf(h2b[1], 0.f), w3v[jB][1], zpb);
            zpb = fmaf(fmaxf(h2b[2], 0.f), w3v[jB][2], zpb);
            zpb = fmaf(fmaxf(h2b[3], 0.f), w3v[jB][3], zpb);
            zpa += __shfl_xor(zpa, 16);
            zpb += __shfl_xor(zpb, 16);

            // lane's own unit: parity selects A/B; fl/b3/ptr hoisted
            const float z  = (par ? zpb : zpa) + b3S[s];
            const float o  = __builtin_amdgcn_rcpf(1.f + __expf(-z));
            const float tv = ptrS[s][pxt];
            const float fo = flS[s] * o;
            inter = fmaf(fo, tv, inter);
            ps    = fmaf(fo, o, ps);
            ts    = fmaf(flS[s], tv * tv, ts);
        }
    }

    // wave reduce then cross-wave
    #pragma unroll
    for (int off = 32; off > 0; off >>= 1) {
        inter += __shfl_down(inter, off);
        ps    += __shfl_down(ps,    off);
        ts    += __shfl_down(ts,    off);
    }
    __shared__ float red[3][4];
    if ((tid & 63) == 0) { red[0][wave] = inter; red[1][wave] = ps; red[2][wave] = ts; }
    __syncthreads();
    if (tid == 0) {
        red_base[(b * 3 + 0) * SLOTS + rest] = red[0][0] + red[0][1] + red[0][2] + red[0][3];
        red_base[(b * 3 + 1) * SLOTS + rest] = red[1][0] + red[1][1] + red[1][2] + red[1][3];
        red_base[(b * 3 + 2) * SLOTS + rest] = red[2][0] + red[2][1] + red[2][2] + red[2][3];
    }
}

// deterministic epilogue: 24 series x 256 partials
__global__ void seg_dice_final(const float* __restrict__ red_base, float* __restrict__ out) {
    __shared__ float red[24][4];
    const int tid = threadIdx.x;  // 128 threads
    if (tid < 96) {
        const int series = tid >> 2;
        const int part   = tid & 3;
        const float4* p = (const float4*)(red_base + series * SLOTS + part * 64);
        float s = 0.f;
        #pragma unroll
        for (int i = 0; i < 16; ++i) { const float4 v = p[i]; s += (v.x + v.y) + (v.z + v.w); }
        red[series][part] = s;
    }
    __syncthreads();
    if (tid == 0) {
        float acc = 0.f;
        #pragma unroll
        for (int b = 0; b < Bb; ++b) {
            const float inter = red[b*3+0][0] + red[b*3+0][1] + red[b*3+0][2] + red[b*3+0][3];
            const float p2    = red[b*3+1][0] + red[b*3+1][1] + red[b*3+1][2] + red[b*3+1][3];
            const float t2    = red[b*3+2][0] + red[b*3+2][1] + red[b*3+2][2] + red[b*3+2][3];
            acc += 1.0f - (2.0f * inter + 1.0f) / (p2 + t2 + 1.0f);
        }
        out[0] = acc * (1.0f / (float)Bb);
    }
}

extern "C" void kernel_launch(void* const* d_in, const int* in_sizes, int n_in,
                              void* d_out, int out_size, void* d_ws, size_t ws_size,
                              hipStream_t stream) {
    const float* seg_feat    = (const float*)d_in[0];
    const float* conv_weight = (const float*)d_in[1];
    const float* mask        = (const float*)d_in[2];
    const int*   ind         = (const int*)d_in[3];
    const float* target      = (const float*)d_in[4];
    float* out = (float*)d_out;

    uint32_t* fragtab  = (uint32_t*)d_ws;
    float*    red_base = (float*)d_ws + FRAG_U32;

    pack_frags<<<256, 64, 0, stream>>>(conv_weight, mask, ind, fragtab);
    seg_dice_main<<<NBLK, 256, 0, stream>>>(seg_feat, target, fragtab, red_base);
    seg_dice_final<<<1, 128, 0, stream>>>(red_base, out);
}

// Round 16
// 36.052 us; speedup vs baseline: 1.6592x; 1.6592x over previous
//
#include <hip/hip_runtime.h>

#define Cc 8
#define Hh 128
#define Ww 128
#define Nn 64
#define Bb 8
#define Dd 169            // (C+2)*C + C + C*C + C + C + 1
#define HW (Hh * Ww)
#define NP 4              // n-pairs per block
#define NPG 8             // n-pair groups per batch (32/NP)
#define PXS 1024          // pixels per stripe (block)
#define NSTRIPE (HW / PXS)          // 16
#define NBLK (Bb * NPG * NSTRIPE)   // 1024 blocks
#define FRAGW 16                    // u32 per lane per n-pair in frag table
#define FRAG_U32 (256 * 64 * FRAGW) // 256 n-pairs total
#define SLOTS (NPG * NSTRIPE)       // 128 reduction slots per batch

#define INV128 (1.0f / 128.0f)

typedef __fp16 f16x2 __attribute__((ext_vector_type(2)));
typedef _Float16 h8 __attribute__((ext_vector_type(8)));
typedef float f32x4 __attribute__((ext_vector_type(4)));

static __device__ __forceinline__ uint32_t pku(float a, float b) {
    f16x2 t = __builtin_amdgcn_cvt_pkrtz(a, b);
    uint32_t u; __builtin_memcpy(&u, &t, 4); return u;
}
static __device__ __forceinline__ h8 u4h8(uint32_t a, uint32_t b, uint32_t c, uint32_t d) {
    uint32_t u[4] = {a, b, c, d}; h8 r; __builtin_memcpy(&r, u, 16); return r;
}

// ---- kernel A: per-lane MFMA fragments per n-pair ----
// Bijections (A and B share them): L1 k = 8g+e (k10 = const-1, bias+x0/y0 fold).
// L2 k2 = 4g+e for e=0..3 (h1 D-rows); NEW k2=16 slot = e4 on g==0: B=1, A=b2[row]
// Slots/lane: [0..3]=A1, [4..6]=A2(+bias elem), [7..10]=w3 f32, [11]=b3, [12]=m^2
__global__ void pack_frags(const float* __restrict__ conv_weight,
                           const float* __restrict__ mask,
                           const int*   __restrict__ ind,
                           uint32_t*    __restrict__ frag) {
    const int npair = blockIdx.x;            // 0..255
    const int b     = npair >> 5;
    const int bn0   = b * Nn + 2 * (npair & 31);
    const int l  = threadIdx.x;              // 0..63
    const int g  = l >> 4, r = l & 15, rr = r & 7;
    const int bnr = bn0 + (r >> 3);          // row-owner n
    const int bng = bn0 + (g >> 1);          // D-row-group owner n
    const float* base = conv_weight + (size_t)b * Dd * HW;
    const float* srcR = base + ind[bnr];
    const float* srcG = base + ind[bng];

    float a1[8];
    #pragma unroll
    for (int e = 0; e < 8; ++e) {
        const int k = 8 * g + e;
        float v = 0.f;
        if (k < 8)       v = srcR[(size_t)(rr * 10 + k) * HW];
        else if (k == 8) v = srcR[(size_t)(rr * 10 + 8) * HW];
        else if (k == 9) v = srcR[(size_t)(rr * 10 + 9) * HW];
        else if (k == 10) {
            const float w8 = srcR[(size_t)(rr * 10 + 8) * HW];
            const float w9 = srcR[(size_t)(rr * 10 + 9) * HW];
            const float b1 = srcR[(size_t)(80 + rr) * HW];
            const int   ib = ind[bnr];
            v = b1 - w8 * ((float)(ib & 127) * INV128)
                   - w9 * ((float)(ib >> 7) * INV128);
        }
        a1[e] = v;
    }
    float a2[4];
    #pragma unroll
    for (int e = 0; e < 4; ++e) {
        const int k2 = 4 * g + e;
        float v = 0.f;
        if (r < 8)  { if (k2 < 8)  v = srcR[(size_t)(88 + rr * 8 + k2) * HW]; }
        else        { if (k2 >= 8) v = srcR[(size_t)(88 + rr * 8 + (k2 - 8)) * HW]; }
        a2[e] = v;
    }
    const float b2bias = (g == 0) ? srcR[(size_t)(152 + rr) * HW] : 0.f;

    float w3v[4];
    #pragma unroll
    for (int j = 0; j < 4; ++j) {
        const int c = (4 * g + j) & 7;
        w3v[j] = srcG[(size_t)(160 + c) * HW];
    }
    const float b3 = srcG[(size_t)168 * HW];
    const float mm = mask[bng];

    uint32_t* dst = frag + ((size_t)npair * 64 + l) * FRAGW;
    dst[0] = pku(a1[0], a1[1]); dst[1] = pku(a1[2], a1[3]);
    dst[2] = pku(a1[4], a1[5]); dst[3] = pku(a1[6], a1[7]);
    dst[4] = pku(a2[0], a2[1]); dst[5] = pku(a2[2], a2[3]);
    dst[6] = pku(b2bias, 0.f);
    float* df = (float*)dst;
    df[7] = w3v[0]; df[8] = w3v[1]; df[9] = w3v[2]; df[10] = w3v[3];
    df[11] = b3; df[12] = mm * mm;
    dst[13] = 0u; dst[14] = 0u; dst[15] = 0u;
}

// ---- kernel B: MFMA main; c2 folded into MFMA, state fits 128 VGPRs ----
__global__ __launch_bounds__(256)
__attribute__((amdgpu_waves_per_eu(4)))
void seg_dice_main(const float* __restrict__ seg_feat,
                   const float* __restrict__ target,
                   const uint32_t* __restrict__ frag,
                   float* __restrict__ red_base) {
    const int bid    = blockIdx.x;
    const int b      = bid & 7;
    const int rest   = bid >> 3;           // 0..127
    const int npg    = rest & 7;
    const int stripe = rest >> 3;          // 0..15
    const int p0     = stripe * PXS;
    const int tid  = threadIdx.x;
    const int wave = tid >> 6;
    const int l    = tid & 63;
    const int g    = l >> 4, col = l & 15;

    __shared__ uint4 lds4[PXS];            // pixel-major seg tile: 8 f16/px

    const float* seg_b = seg_feat + (size_t)b * Cc * HW;
    #pragma unroll
    for (int q = 0; q < 4; ++q) {
        const int px = q * 256 + tid;
        float v[8];
        #pragma unroll
        for (int c = 0; c < 8; ++c) v[c] = seg_b[(size_t)c * HW + p0 + px];
        lds4[px] = uint4{pku(v[0], v[1]), pku(v[2], v[3]),
                         pku(v[4], v[5]), pku(v[6], v[7])};
    }

    // per-lane fragments for NP n-pairs (b3/fl folded straight to parity slots)
    const int npair0 = b * 32 + npg * NP;
    const int par = g & 1;
    uint32_t A1u[NP][4], A2u[NP][3];
    float w3v[NP][4];
    float flS[2], b3S[2];
    const float* ptrS[2];
    #pragma unroll
    for (int j = 0; j < NP; ++j) {
        const uint4* fp = (const uint4*)(frag + ((size_t)(npair0 + j) * 64 + l) * FRAGW);
        const uint4 q0 = fp[0], q1 = fp[1], q2 = fp[2];
        const uint32_t q3x = ((const uint32_t*)fp)[12];
        A1u[j][0] = q0.x; A1u[j][1] = q0.y; A1u[j][2] = q0.z; A1u[j][3] = q0.w;
        A2u[j][0] = q1.x; A2u[j][1] = q1.y; A2u[j][2] = q1.z;
        w3v[j][0] = __uint_as_float(q1.w);
        w3v[j][1] = __uint_as_float(q2.x);
        w3v[j][2] = __uint_as_float(q2.y);
        w3v[j][3] = __uint_as_float(q2.z);
        const int s = j >> 1;
        if ((j & 1) == par) {               // lane's own unit in slot s
            b3S[s] = __uint_as_float(q2.w);
            flS[s] = __uint_as_float(q3x);
            const int bnS = b * Nn + 2 * (npg * NP + j) + (l >> 5);
            ptrS[s] = target + (size_t)bnS * HW + p0 + col;
        }
    }
    __syncthreads();

    const uint32_t one16 = 0x3C00u;                       // f16 1.0 in low half
    const uint32_t b2one = (g == 0) ? one16 : 0u;         // B2 bias-k slot
    const f32x4 ZF = {0.f, 0.f, 0.f, 0.f};
    float inter = 0.f, ps = 0.f, ts = 0.f;

    #pragma unroll 1
    for (int tt = wave; tt < PXS / 16; tt += 4) {
        const int pxt = tt * 16;
        const int pxg = p0 + pxt + col;

        const uint4 d = lds4[pxt + col];
        const uint32_t xv = pku((float)(pxg & 127) * INV128,
                                (float)(pxg >> 7) * INV128);
        const uint32_t e0 = (g == 0) ? d.x : ((g == 1) ? xv : 0u);
        const uint32_t e1 = (g == 0) ? d.y : ((g == 1) ? one16 : 0u);
        const uint32_t e2 = (g == 0) ? d.z : 0u;
        const uint32_t e3 = (g == 0) ? d.w : 0u;
        const h8 B1 = u4h8(e0, e1, e2, e3);

        #pragma unroll
        for (int s = 0; s < 2; ++s) {
            const int jA = 2 * s, jB = 2 * s + 1;
            const h8 A1a = u4h8(A1u[jA][0], A1u[jA][1], A1u[jA][2], A1u[jA][3]);
            const h8 A1b = u4h8(A1u[jB][0], A1u[jB][1], A1u[jB][2], A1u[jB][3]);
            f32x4 h1a = __builtin_amdgcn_mfma_f32_16x16x32_f16(A1a, B1, ZF, 0, 0, 0);
            f32x4 h1b = __builtin_amdgcn_mfma_f32_16x16x32_f16(A1b, B1, ZF, 0, 0, 0);
            #pragma unroll
            for (int e = 0; e < 4; ++e) {
                h1a[e] = fmaxf(h1a[e], 0.f);
                h1b[e] = fmaxf(h1b[e], 0.f);
            }
            const h8 B2a = u4h8(pku(h1a[0], h1a[1]), pku(h1a[2], h1a[3]), b2one, 0u);
            const h8 B2b = u4h8(pku(h1b[0], h1b[1]), pku(h1b[2], h1b[3]), b2one, 0u);
            const h8 A2a = u4h8(A2u[jA][0], A2u[jA][1], A2u[jA][2], 0u);
            const h8 A2b = u4h8(A2u[jB][0], A2u[jB][1], A2u[jB][2], 0u);
            f32x4 h2a = __builtin_amdgcn_mfma_f32_16x16x32_f16(A2a, B2a, ZF, 0, 0, 0);
            f32x4 h2b = __builtin_amdgcn_mfma_f32_16x16x32_f16(A2b, B2b, ZF, 0, 0, 0);

            float zpa = fmaxf(h2a[0], 0.f) * w3v[jA][0];
            zpa = fmaf(fmaxf(h2a[1], 0.f), w3v[jA][1], zpa);
            zpa = fmaf(fmaxf(h2a[2], 0.f), w3v[jA][2], zpa);
            zpa = fmaf(fmaxf(h2a[3], 0.f), w3v[jA][3], zpa);
            float zpb = fmaxf(h2b[0], 0.f) * w3v[jB][0];
            zpb = fmaf(fmaxf(h2b[1], 0.f), w3v[jB][1], zpb);
            zpb = fmaf(fmaxf(h2b[2], 0.f), w3v[jB][2], zpb);
            zpb = fmaf(fmaxf(h2b[3], 0.f), w3v[jB][3], zpb);
            zpa += __shfl_xor(zpa, 16);
            zpb += __shfl_xor(zpb, 16);

            const float z  = (par ? zpb : zpa) + b3S[s];
            const float o  = __builtin_amdgcn_rcpf(1.f + __expf(-z));
            const float tv = ptrS[s][pxt];
            const float fo = flS[s] * o;
            inter = fmaf(fo, tv, inter);
            ps    = fmaf(fo, o, ps);
            ts    = fmaf(flS[s], tv * tv, ts);
        }
    }

    // wave reduce then cross-wave
    #pragma unroll
    for (int off = 32; off > 0; off >>= 1) {
        inter += __shfl_down(inter, off);
        ps    += __shfl_down(ps,    off);
        ts    += __shfl_down(ts,    off);
    }
    __shared__ float red[3][4];
    if ((tid & 63) == 0) { red[0][wave] = inter; red[1][wave] = ps; red[2][wave] = ts; }
    __syncthreads();
    if (tid == 0) {
        red_base[(b * 3 + 0) * SLOTS + rest] = red[0][0] + red[0][1] + red[0][2] + red[0][3];
        red_base[(b * 3 + 1) * SLOTS + rest] = red[1][0] + red[1][1] + red[1][2] + red[1][3];
        red_base[(b * 3 + 2) * SLOTS + rest] = red[2][0] + red[2][1] + red[2][2] + red[2][3];
    }
}

// deterministic epilogue: 24 series x 128 partials
__global__ void seg_dice_final(const float* __restrict__ red_base, float* __restrict__ out) {
    __shared__ float red[24][4];
    const int tid = threadIdx.x;  // 128 threads
    if (tid < 96) {
        const int series = tid >> 2;
        const int part   = tid & 3;
        const float4* p = (const float4*)(red_base + series * SLOTS + part * 32);
        float s = 0.f;
        #pragma unroll
        for (int i = 0; i < 8; ++i) { const float4 v = p[i]; s += (v.x + v.y) + (v.z + v.w); }
        red[series][part] = s;
    }
    __syncthreads();
    if (tid == 0) {
        float acc = 0.f;
        #pragma unroll
        for (int b = 0; b < Bb; ++b) {
            const float inter = red[b*3+0][0] + red[b*3+0][1] + red[b*3+0][2] + red[b*3+0][3];
            const float p2    = red[b*3+1][0] + red[b*3+1][1] + red[b*3+1][2] + red[b*3+1][3];
            const float t2    = red[b*3+2][0] + red[b*3+2][1] + red[b*3+2][2] + red[b*3+2][3];
            acc += 1.0f - (2.0f * inter + 1.0f) / (p2 + t2 + 1.0f);
        }
        out[0] = acc * (1.0f / (float)Bb);
    }
}

extern "C" void kernel_launch(void* const* d_in, const int* in_sizes, int n_in,
                              void* d_out, int out_size, void* d_ws, size_t ws_size,
                              hipStream_t stream) {
    const float* seg_feat    = (const float*)d_in[0];
    const float* conv_weight = (const float*)d_in[1];
    const float* mask        = (const float*)d_in[2];
    const int*   ind         = (const int*)d_in[3];
    const float* target      = (const float*)d_in[4];
    float* out = (float*)d_out;

    uint32_t* fragtab  = (uint32_t*)d_ws;
    float*    red_base = (float*)d_ws + FRAG_U32;

    pack_frags<<<256, 64, 0, stream>>>(conv_weight, mask, ind, fragtab);
    seg_dice_main<<<NBLK, 256, 0, stream>>>(seg_feat, target, fragtab, red_base);
    seg_dice_final<<<1, 128, 0, stream>>>(red_base, out);
}